// Round 10
// baseline (282.445 us; speedup 1.0000x reference)
//
#include <hip/hip_runtime.h>
#include <hip/hip_fp16.h>

#define TPB 256
#define RNG 128          // nodes per range
#define RSH 7            // log2(RNG)
#define SH  8            // shards (one per XCD via blockIdx&7)
#define CAP 512          // per-(shard,range) cell capacity (mean ~257, ~16 sigma)

// ---------------------------------------------------------------------------
// GCN, fully commuted (aggregate only at width 16):
//   hsx = fp16(dinv*x) [N,16];  z = fp16((relu(dinv*agg@W1+b1)*dinv)@Wf) [N,16]
//   out = dinv*(z[n]+sum z[s]) + bf      (Wf = W2@WL, bf = b2@WL + bL)
// Build (deterministic edge SETS; order-racy only, like R8):
//   placeD: single-pass edges -> cells gbuf[(j*C+r)*CAP + cursor], j=blockIdx&7
//           (shard-major: each XCD's cursors+data in its own L2 region)
//   scanR:  1-block prefix of per-range totals -> rbase
//   sort2C: per-range LDS node sort of the 8 cells -> bucketS/start/dinv/hsx
// Aggregation: R8's fixed-partition strand gathers + shfl trees (NO fp atomics
// -> replay-stable; LDS fp32 atomics failed the tripwire in R9).
// ---------------------------------------------------------------------------

__device__ inline void acc4(float a[4], uint2 u) {
    __half2 h0 = *(__half2*)&u.x, h1 = *(__half2*)&u.y;
    float2 f0 = __half22float2(h0), f1 = __half22float2(h1);
    a[0] += f0.x; a[1] += f0.y; a[2] += f1.x; a[3] += f1.y;
}

// Wf/bf fusion + gcur zeroing (replaces memset dispatch)
__global__ void k_wfuse(const float* __restrict__ W2, const float* __restrict__ WL,
                        const float* __restrict__ b2, const float* __restrict__ bL,
                        float* __restrict__ Wf, float* __restrict__ bf,
                        int* __restrict__ gcur, int NCELL) {
    int gid = blockIdx.x * TPB + threadIdx.x;     // 4 blocks * 256 = 1024
    for (int i = gid; i < NCELL; i += 4 * TPB) gcur[i] = 0;
    int k = gid >> 4, o = gid & 15;
    if (k < 64) {
        float s = 0.f;
#pragma unroll 8
        for (int j = 0; j < 128; j++) s += W2[k * 128 + j] * WL[j * 16 + o];
        Wf[gid] = s;
    }
    if (gid < 16) {
        float s = bL[gid];
        for (int j = 0; j < 128; j++) s += b2[j] * WL[j * 16 + gid];
        bf[gid] = s;
    }
}

// single-pass placement: 4 edges/thread (int4), direct atomic cell cursors
__global__ void k_placeD(const int* __restrict__ ei, int* __restrict__ gcur,
                         int* __restrict__ gbuf, int E, int C) {
    int gid = blockIdx.x * TPB + threadIdx.x;
    int j = blockIdx.x & (SH - 1);
    int nq = E >> 2;                               // E divisible by 4
    if (gid >= nq) return;
    int4 s4 = ((const int4*)ei)[gid];
    int4 d4 = ((const int4*)ei)[nq + gid];         // = ei + E + 4*gid
    int ss[4] = {s4.x, s4.y, s4.z, s4.w};
    int dd[4] = {d4.x, d4.y, d4.z, d4.w};
#pragma unroll
    for (int i = 0; i < 4; i++) {
        int cell = j * C + (dd[i] >> RSH);         // shard-major
        int pos = atomicAdd(&gcur[cell], 1);
        if (pos < CAP) gbuf[cell * CAP + pos] = (ss[i] << RSH) | (dd[i] & (RNG - 1));
    }
}

// 1-block exclusive prefix of per-range totals -> rbase[C+1]
__global__ void k_scanR(const int* __restrict__ gcur, int* __restrict__ rbase, int C) {
    __shared__ int ssum[TPB];
    int t = threadIdx.x;
    int CH = (C + TPB - 1) / TPB;
    int lo = t * CH, hi = min(C, lo + CH);
    int s = 0;
    for (int r = lo; r < hi; r++)
        for (int j = 0; j < SH; j++) s += min(gcur[j * C + r], CAP);
    ssum[t] = s;
    __syncthreads();
    for (int off = 1; off < TPB; off <<= 1) {
        int v = (t >= off) ? ssum[t - off] : 0;
        __syncthreads();
        ssum[t] += v;
        __syncthreads();
    }
    int base = (t == 0) ? 0 : ssum[t - 1];
    for (int r = lo; r < hi; r++) {
        rbase[r] = base;
        for (int j = 0; j < SH; j++) base += min(gcur[j * C + r], CAP);
    }
    if (t == TPB - 1) rbase[C] = base;
}

// per-range node-sort of cells -> bucketS/start/dinv; fused hsx = fp16(dinv*x)
__global__ void k_sort2C(const int* __restrict__ gbuf, const int* __restrict__ gcur,
                         const int* __restrict__ rbase, const float* __restrict__ x,
                         int* __restrict__ bucketS, int* __restrict__ start,
                         float* __restrict__ dinv, __half2* __restrict__ hsx,
                         int N, int C) {
    __shared__ int cnt[RNG];
    __shared__ int offs[RNG];
    __shared__ int cur[RNG];
    __shared__ float sdi[RNG];
    int t = threadIdx.x, r = blockIdx.x;
    if (t < RNG) cnt[t] = 0;
    __syncthreads();
    for (int j = 0; j < SH; j++) {
        int cell = j * C + r;
        int m = min(gcur[cell], CAP);
        const int* src = gbuf + cell * CAP;
        for (int i = t; i < m; i += TPB)
            atomicAdd(&cnt[src[i] & (RNG - 1)], 1);
    }
    __syncthreads();
    if (t < RNG) offs[t] = cnt[t];
    __syncthreads();
    for (int off = 1; off < RNG; off <<= 1) {     // Hillis-Steele inclusive scan
        int v = 0;
        if (t < RNG && t >= off) v = offs[t - off];
        __syncthreads();
        if (t < RNG) offs[t] += v;
        __syncthreads();
    }
    int base = rbase[r];
    if (t < RNG) {
        int ex = offs[t] - cnt[t];                // exclusive
        cur[t] = ex;
        float di = rsqrtf((float)cnt[t] + 1.0f);  // +1 self-loop
        sdi[t] = di;
        int n = r * RNG + t;
        if (n < N) { start[n] = base + ex; dinv[n] = di; }
    }
    if (r == 0 && t == 0) start[N] = rbase[C];    // CSR sentinel
    __syncthreads();
    for (int j = 0; j < SH; j++) {
        int cell = j * C + r;
        int m = min(gcur[cell], CAP);
        const int* src = gbuf + cell * CAP;
        for (int i = t; i < m; i += TPB) {
            int p = src[i];
            int pos = base + atomicAdd(&cur[p & (RNG - 1)], 1);
            bucketS[pos] = p >> RSH;
        }
    }
    // fused: hsx[n][:] = fp16(dinv[n] * x[n][:]) — 128 nodes x 8 half2
    for (int idx = t; idx < RNG * 8; idx += TPB) {
        int ln = idx >> 3, f2 = idx & 7;
        int n = r * RNG + ln;
        if (n < N) {
            float2 xv = ((const float2*)x)[(size_t)n * 8 + f2];
            float dn = sdi[ln];
            hsx[(size_t)n * 8 + f2] = __floats2half2_rn(xv.x * dn, xv.y * dn);
        }
    }
}

// layer 1 + projection: wave handles 4 nodes (R8-proven, replay-stable)
__global__ void k_l1f(const int* __restrict__ bucketS, const int* __restrict__ start,
                      const uint2* __restrict__ hsx, const float* __restrict__ W1,
                      const float* __restrict__ b1, const float* __restrict__ Wf,
                      const float* __restrict__ dinv, __half2* __restrict__ z, int N) {
    __shared__ float w1[16 * 64];                 // [k][j], 2-way banks only
    __shared__ float wfp[64 * 17];                // [j][o] padded -> 2-way only
    __shared__ float sb1[64];
    __shared__ float aggrow[4][16];
    __shared__ float vrow[4][64];
    int t = threadIdx.x;
    for (int i = t; i < 16 * 64; i += TPB) w1[i] = W1[i];
    for (int i = t; i < 64 * 16; i += TPB) wfp[(i >> 4) * 17 + (i & 15)] = Wf[i];
    if (t < 64) sb1[t] = b1[t];
    __syncthreads();
    int wid = t >> 6, lane = t & 63;
    int g = lane >> 2, q = lane & 3;              // 16 strands x 4 uint2 slots
    int part = lane >> 4, o = lane & 15;
#pragma unroll
    for (int nn = 0; nn < 4; nn++) {
        int n = (blockIdx.x * 4 + wid) * 4 + nn;
        if (n >= N) continue;
        int base = start[n], d = start[n + 1] - base;
        float a[4] = {0.f, 0.f, 0.f, 0.f};
        if (g == 0) acc4(a, hsx[(size_t)n * 4 + q]);      // self-loop
        for (int k = g; k < d; k += 16)
            acc4(a, hsx[(size_t)bucketS[base + k] * 4 + q]);
#pragma unroll
        for (int m = 4; m <= 32; m <<= 1)
#pragma unroll
            for (int i = 0; i < 4; i++) a[i] += __shfl_xor(a[i], m);
        if (g == 0) {
#pragma unroll
            for (int i = 0; i < 4; i++) aggrow[wid][q * 4 + i] = a[i];
        }
        // wave-coherent LDS round-trip (same wave wrote aggrow[wid])
        float dn = dinv[n];
        float v = 0.f;
#pragma unroll
        for (int k = 0; k < 16; k++) v += aggrow[wid][k] * w1[k * 64 + lane];
        v = fmaxf(dn * v + sb1[lane], 0.f) * dn;  // h1*dinv, lane j holds v_j
        vrow[wid][lane] = v;
        float s = 0.f;
#pragma unroll
        for (int jj = 0; jj < 16; jj++)
            s += vrow[wid][part * 16 + jj] * wfp[(part * 16 + jj) * 17 + o];
        s += __shfl_xor(s, 16);
        s += __shfl_xor(s, 32);
        float pv = __shfl(s, lane | 1);           // even lane grabs odd neighbor
        if (part == 0 && !(lane & 1))
            z[(size_t)n * 8 + (o >> 1)] = __floats2half2_rn(s, pv);
    }
}

// layer 2 aggregation of projected z + bias: out = dinv*(z[n]+sum z[s]) + bf
__global__ void k_l3(const int* __restrict__ bucketS, const int* __restrict__ start,
                     const uint2* __restrict__ z, const float* __restrict__ bfv,
                     const float* __restrict__ dinv, float* __restrict__ out, int N) {
    __shared__ float sbf[16];
    int t = threadIdx.x;
    if (t < 16) sbf[t] = bfv[t];
    __syncthreads();
    int wid = t >> 6, lane = t & 63;
    int g = lane >> 2, q = lane & 3;              // 16 strands x 4 uint2 slots
#pragma unroll
    for (int nn = 0; nn < 4; nn++) {
        int n = (blockIdx.x * 4 + wid) * 4 + nn;
        if (n >= N) continue;
        int base = start[n], d = start[n + 1] - base;
        float a[4] = {0.f, 0.f, 0.f, 0.f};
        if (g == 0) acc4(a, z[(size_t)n * 4 + q]);        // self-loop
        for (int k = g; k < d; k += 16)
            acc4(a, z[(size_t)bucketS[base + k] * 4 + q]);
#pragma unroll
        for (int m = 4; m <= 32; m <<= 1)
#pragma unroll
            for (int i = 0; i < 4; i++) a[i] += __shfl_xor(a[i], m);
        if (g == 0) {
            float dn = dinv[n];
            float4 r;
            r.x = dn * a[0] + sbf[q * 4 + 0];
            r.y = dn * a[1] + sbf[q * 4 + 1];
            r.z = dn * a[2] + sbf[q * 4 + 2];
            r.w = dn * a[3] + sbf[q * 4 + 3];
            ((float4*)out)[(size_t)n * 4 + q] = r;
        }
    }
}

extern "C" void kernel_launch(void* const* d_in, const int* in_sizes, int n_in,
                              void* d_out, int out_size, void* d_ws, size_t ws_size,
                              hipStream_t stream) {
    const float* x  = (const float*)d_in[0];
    const int*   ei = (const int*)d_in[1];
    const float* W1 = (const float*)d_in[2];
    const float* b1 = (const float*)d_in[3];
    const float* W2 = (const float*)d_in[4];
    const float* b2 = (const float*)d_in[5];
    const float* WL = (const float*)d_in[6];
    const float* bL = (const float*)d_in[7];
    float* out = (float*)d_out;

    const int N     = in_sizes[0] / 16;       // 100000
    const int E     = in_sizes[1] / 2;        // 1600000
    const int C     = (N + RNG - 1) >> RSH;   // 782 ranges
    const int NCELL = C * SH;                 // 6256 cells

    // ws ints: gbuf[NCELL*CAP] | gcur[NCELL] | rbase[C+1] | bucketS[E] | start[N+1] | pad
    //   floats: dinv[N] | Wf[1024] | bf[16] | pad | hsx[8N half2] | z[8N half2]
    int* wsi     = (int*)d_ws;
    int* gbuf    = wsi;
    int* gcur    = gbuf + (size_t)NCELL * CAP;
    int* rbase   = gcur + NCELL;
    int* bucketS = rbase + C + 1;
    int* start   = bucketS + E;
    size_t off   = (size_t)NCELL * CAP + NCELL + (C + 1) + E + (N + 1);
    off = (off + 3) & ~(size_t)3;
    float* dinv = (float*)(wsi + off);
    float* Wf   = dinv + N;
    float* bf   = Wf + 1024;
    off = off + N + 1024 + 16;
    off = (off + 3) & ~(size_t)3;                 // 16B-align fp16 section
    __half2* hsx = (__half2*)(wsi + off);         // 8N half2
    __half2* z   = (__half2*)(wsi + off + (size_t)8 * N);

    // Wf/bf fusion + gcur zero
    k_wfuse<<<4, TPB, 0, stream>>>(W2, WL, b2, bL, Wf, bf, gcur, NCELL);

    // single-pass sharded cell placement
    const int NP = (E / 4 + TPB - 1) / TPB;
    k_placeD<<<NP, TPB, 0, stream>>>(ei, gcur, gbuf, E, C);

    // per-range totals prefix
    k_scanR<<<1, TPB, 0, stream>>>(gcur, rbase, C);

    // per-range node sort -> CSR + dinv + fp16 hsx
    k_sort2C<<<C, TPB, 0, stream>>>(gbuf, gcur, rbase, x, bucketS, start, dinv, hsx, N, C);

    // layer 1 + projection -> z fp16 [N,16]
    const int NBLK = (N + 15) / 16;               // 16 nodes per block (4/wave)
    k_l1f<<<NBLK, TPB, 0, stream>>>(bucketS, start, (const uint2*)hsx, W1, b1, Wf, dinv, z, N);

    // layer 2 aggregation + bias -> out
    k_l3<<<NBLK, TPB, 0, stream>>>(bucketS, start, (const uint2*)z, bf, dinv, out, N);
}

// Round 11
// 220.723 us; speedup vs baseline: 1.2796x; 1.2796x over previous
//
#include <hip/hip_runtime.h>
#include <hip/hip_fp16.h>

#define TPB 256
#define RNG 128          // nodes per range
#define RSH 7            // log2(RNG)
#define MAXC 1024        // max ranges supported by LDS hist (N <= 131072)
#define EPB 8192         // edges per block in hist/place (chunk ~10.5 edges)

// ---------------------------------------------------------------------------
// GCN, fully commuted (aggregate only at width 16):
//   hsx = fp16(dinv*x) [N,16];  z = fp16((relu(dinv*agg@W1+b1)*dinv)@Wf) [N,16]
//   out = dinv*(z[n]+sum z[s]) + bf      (Wf = W2@WL, bf = b2@WL + bL)
// Build: R8-proven 2-phase counting sort (LDS-chunk writes -- no XCD-mapping
// assumption, no per-edge global atomics), EPB=8192 + int4 edge loads:
//   hist: LDS histogram by dst-range -> ghist[(range,shard)]
//   scan: 1-block prefix -> gbase/gcur
//   place: per-block LDS hist -> chunk reservation -> chunked packed writes
//   sort2: per-range LDS node sort -> bucketS/start/dinv + fp16 hsx
// Aggregation: fixed-partition strand gathers + shfl trees (NO fp atomics ->
// replay-stable; LDS fp32 atomics failed the tripwire in R9).
// ---------------------------------------------------------------------------

__device__ inline void acc4(float a[4], uint2 u) {
    __half2 h0 = *(__half2*)&u.x, h1 = *(__half2*)&u.y;
    float2 f0 = __half22float2(h0), f1 = __half22float2(h1);
    a[0] += f0.x; a[1] += f0.y; a[2] += f1.x; a[3] += f1.y;
}

// Wf/bf fusion + ghist zeroing (replaces memset dispatch)
__global__ void k_wfuse(const float* __restrict__ W2, const float* __restrict__ WL,
                        const float* __restrict__ b2, const float* __restrict__ bL,
                        float* __restrict__ Wf, float* __restrict__ bf,
                        int* __restrict__ ghist, int L) {
    int gid = blockIdx.x * TPB + threadIdx.x;     // 4 blocks * 256 = 1024
    for (int i = gid; i < L; i += 4 * TPB) ghist[i] = 0;
    int k = gid >> 4, o = gid & 15;
    if (k < 64) {
        float s = 0.f;
#pragma unroll 8
        for (int j = 0; j < 128; j++) s += W2[k * 128 + j] * WL[j * 16 + o];
        Wf[gid] = s;
    }
    if (gid < 16) {
        float s = bL[gid];
        for (int j = 0; j < 128; j++) s += b2[j] * WL[j * 16 + gid];
        bf[gid] = s;
    }
}

// per-block LDS histogram of dst-range (int4 loads), merged into ghist[c*8+j]
__global__ void k_hist(const int* __restrict__ ei, int* __restrict__ ghist,
                       int E, int C) {
    __shared__ int h[MAXC];
    int t = threadIdx.x, b = blockIdx.x, j = b & 7;
    for (int c = t; c < C; c += TPB) h[c] = 0;
    __syncthreads();
    const int4* d4p = (const int4*)(ei + E);
    int nq = E >> 2;
    int qbase = b * (EPB / 4);
    for (int it = 0; it < EPB / (4 * TPB); it++) {
        int q = qbase + it * TPB + t;
        if (q < nq) {
            int4 d = d4p[q];
            atomicAdd(&h[d.x >> RSH], 1);
            atomicAdd(&h[d.y >> RSH], 1);
            atomicAdd(&h[d.z >> RSH], 1);
            atomicAdd(&h[d.w >> RSH], 1);
        }
    }
    __syncthreads();
    for (int c = t; c < C; c += TPB) {
        int v = h[c];
        if (v) atomicAdd(&ghist[c * 8 + j], v);
    }
}

// single-block exclusive scan of ghist[0..L) -> gbase (+sentinel), gcur copy
__global__ void k_scan(const int* __restrict__ ghist, int* __restrict__ gbase,
                       int* __restrict__ gcur, int L) {
    __shared__ int ssum[TPB];
    int t = threadIdx.x;
    int CH = (L + TPB - 1) / TPB;
    int lo = t * CH, hi = min(L, lo + CH);
    int s = 0;
    for (int i = lo; i < hi; i++) s += ghist[i];
    ssum[t] = s;
    __syncthreads();
    for (int off = 1; off < TPB; off <<= 1) {
        int v = (t >= off) ? ssum[t - off] : 0;
        __syncthreads();
        ssum[t] += v;
        __syncthreads();
    }
    int base = (t == 0) ? 0 : ssum[t - 1];
    for (int i = lo; i < hi; i++) { gbase[i] = base; gcur[i] = base; base += ghist[i]; }
    if (t == TPB - 1) gbase[L] = base;            // = E
}

// place packed (src<<7 | dst&127) into range-sorted gbuf; chunk reservation.
// EPB=8192 -> mean chunk 10.5 edges -> near-dense 4B writes.
__global__ void k_place(const int* __restrict__ ei, int* __restrict__ gcur,
                        unsigned* __restrict__ gbuf, int E, int C) {
    __shared__ int h[MAXC];
    int t = threadIdx.x, b = blockIdx.x, j = b & 7;
    for (int c = t; c < C; c += TPB) h[c] = 0;
    __syncthreads();
    const int4* s4p = (const int4*)ei;
    const int4* d4p = (const int4*)(ei + E);
    int nq = E >> 2;
    int qbase = b * (EPB / 4);
    for (int it = 0; it < EPB / (4 * TPB); it++) {  // pass 1: count
        int q = qbase + it * TPB + t;
        if (q < nq) {
            int4 d = d4p[q];
            atomicAdd(&h[d.x >> RSH], 1);
            atomicAdd(&h[d.y >> RSH], 1);
            atomicAdd(&h[d.z >> RSH], 1);
            atomicAdd(&h[d.w >> RSH], 1);
        }
    }
    __syncthreads();
    for (int c = t; c < C; c += TPB) {            // reserve chunk per (c, shard)
        int v = h[c];
        if (v) h[c] = atomicAdd(&gcur[c * 8 + j], v);
    }
    __syncthreads();
    for (int it = 0; it < EPB / (4 * TPB); it++) {  // pass 2: chunked place
        int q = qbase + it * TPB + t;
        if (q < nq) {
            int4 s = s4p[q];
            int4 d = d4p[q];
            int p0 = atomicAdd(&h[d.x >> RSH], 1);
            gbuf[p0] = ((unsigned)s.x << RSH) | (unsigned)(d.x & (RNG - 1));
            int p1 = atomicAdd(&h[d.y >> RSH], 1);
            gbuf[p1] = ((unsigned)s.y << RSH) | (unsigned)(d.y & (RNG - 1));
            int p2 = atomicAdd(&h[d.z >> RSH], 1);
            gbuf[p2] = ((unsigned)s.z << RSH) | (unsigned)(d.z & (RNG - 1));
            int p3 = atomicAdd(&h[d.w >> RSH], 1);
            gbuf[p3] = ((unsigned)s.w << RSH) | (unsigned)(d.w & (RNG - 1));
        }
    }
}

// per-range node-sort -> bucketS/start/dinv; fused hsx = fp16(dinv*x)
__global__ void k_sort2(const unsigned* __restrict__ gbuf, const int* __restrict__ gbase,
                        const float* __restrict__ x,
                        int* __restrict__ bucketS, int* __restrict__ start,
                        float* __restrict__ dinv, __half2* __restrict__ hsx,
                        int N, int E) {
    __shared__ int cnt[RNG];
    __shared__ int offs[RNG];
    __shared__ int cur[RNG];
    __shared__ float sdi[RNG];
    int t = threadIdx.x, r = blockIdx.x;
    if (t < RNG) cnt[t] = 0;
    __syncthreads();
    int lo = gbase[r * 8], hi = gbase[r * 8 + 8];
    for (int i = lo + t; i < hi; i += TPB)
        atomicAdd(&cnt[gbuf[i] & (RNG - 1)], 1);
    __syncthreads();
    if (t < RNG) offs[t] = cnt[t];
    __syncthreads();
    for (int off = 1; off < RNG; off <<= 1) {     // Hillis-Steele inclusive scan
        int v = 0;
        if (t < RNG && t >= off) v = offs[t - off];
        __syncthreads();
        if (t < RNG) offs[t] += v;
        __syncthreads();
    }
    if (t < RNG) {
        int ex = offs[t] - cnt[t];                // exclusive
        cur[t] = ex;
        float di = rsqrtf((float)cnt[t] + 1.0f);  // +1 self-loop
        sdi[t] = di;
        int n = r * RNG + t;
        if (n < N) { start[n] = lo + ex; dinv[n] = di; }
    }
    if (r == 0 && t == 0) start[N] = E;           // CSR sentinel
    __syncthreads();
    for (int i = lo + t; i < hi; i += TPB) {
        unsigned p = gbuf[i];
        int pos = lo + atomicAdd(&cur[p & (RNG - 1)], 1);
        bucketS[pos] = (int)(p >> RSH);
    }
    // fused: hsx[n][:] = fp16(dinv[n] * x[n][:]) — 128 nodes x 8 half2
    for (int idx = t; idx < RNG * 8; idx += TPB) {
        int ln = idx >> 3, f2 = idx & 7;
        int n = r * RNG + ln;
        if (n < N) {
            float2 xv = ((const float2*)x)[(size_t)n * 8 + f2];
            float dn = sdi[ln];
            hsx[(size_t)n * 8 + f2] = __floats2half2_rn(xv.x * dn, xv.y * dn);
        }
    }
}

// layer 1 + projection: wave handles 4 nodes (replay-stable strand gathers)
__global__ void k_l1f(const int* __restrict__ bucketS, const int* __restrict__ start,
                      const uint2* __restrict__ hsx, const float* __restrict__ W1,
                      const float* __restrict__ b1, const float* __restrict__ Wf,
                      const float* __restrict__ dinv, __half2* __restrict__ z, int N) {
    __shared__ float w1[16 * 64];                 // [k][j], 2-way banks only
    __shared__ float wfp[64 * 17];                // [j][o] padded -> 2-way only
    __shared__ float sb1[64];
    __shared__ float aggrow[4][16];
    __shared__ float vrow[4][64];
    int t = threadIdx.x;
    for (int i = t; i < 16 * 64; i += TPB) w1[i] = W1[i];
    for (int i = t; i < 64 * 16; i += TPB) wfp[(i >> 4) * 17 + (i & 15)] = Wf[i];
    if (t < 64) sb1[t] = b1[t];
    __syncthreads();
    int wid = t >> 6, lane = t & 63;
    int g = lane >> 2, q = lane & 3;              // 16 strands x 4 uint2 slots
    int part = lane >> 4, o = lane & 15;
#pragma unroll
    for (int nn = 0; nn < 4; nn++) {
        int n = (blockIdx.x * 4 + wid) * 4 + nn;
        if (n >= N) continue;
        int base = start[n], d = start[n + 1] - base;
        float a[4] = {0.f, 0.f, 0.f, 0.f};
        if (g == 0) acc4(a, hsx[(size_t)n * 4 + q]);      // self-loop
        for (int k = g; k < d; k += 16)
            acc4(a, hsx[(size_t)bucketS[base + k] * 4 + q]);
#pragma unroll
        for (int m = 4; m <= 32; m <<= 1)
#pragma unroll
            for (int i = 0; i < 4; i++) a[i] += __shfl_xor(a[i], m);
        if (g == 0) {
#pragma unroll
            for (int i = 0; i < 4; i++) aggrow[wid][q * 4 + i] = a[i];
        }
        // wave-coherent LDS round-trip (same wave wrote aggrow[wid])
        float dn = dinv[n];
        float v = 0.f;
#pragma unroll
        for (int k = 0; k < 16; k++) v += aggrow[wid][k] * w1[k * 64 + lane];
        v = fmaxf(dn * v + sb1[lane], 0.f) * dn;  // h1*dinv, lane j holds v_j
        vrow[wid][lane] = v;
        float s = 0.f;
#pragma unroll
        for (int jj = 0; jj < 16; jj++)
            s += vrow[wid][part * 16 + jj] * wfp[(part * 16 + jj) * 17 + o];
        s += __shfl_xor(s, 16);
        s += __shfl_xor(s, 32);
        float pv = __shfl(s, lane | 1);           // even lane grabs odd neighbor
        if (part == 0 && !(lane & 1))
            z[(size_t)n * 8 + (o >> 1)] = __floats2half2_rn(s, pv);
    }
}

// layer 2 aggregation of projected z + bias: out = dinv*(z[n]+sum z[s]) + bf
__global__ void k_l3(const int* __restrict__ bucketS, const int* __restrict__ start,
                     const uint2* __restrict__ z, const float* __restrict__ bfv,
                     const float* __restrict__ dinv, float* __restrict__ out, int N) {
    __shared__ float sbf[16];
    int t = threadIdx.x;
    if (t < 16) sbf[t] = bfv[t];
    __syncthreads();
    int wid = t >> 6, lane = t & 63;
    int g = lane >> 2, q = lane & 3;              // 16 strands x 4 uint2 slots
#pragma unroll
    for (int nn = 0; nn < 4; nn++) {
        int n = (blockIdx.x * 4 + wid) * 4 + nn;
        if (n >= N) continue;
        int base = start[n], d = start[n + 1] - base;
        float a[4] = {0.f, 0.f, 0.f, 0.f};
        if (g == 0) acc4(a, z[(size_t)n * 4 + q]);        // self-loop
        for (int k = g; k < d; k += 16)
            acc4(a, z[(size_t)bucketS[base + k] * 4 + q]);
#pragma unroll
        for (int m = 4; m <= 32; m <<= 1)
#pragma unroll
            for (int i = 0; i < 4; i++) a[i] += __shfl_xor(a[i], m);
        if (g == 0) {
            float dn = dinv[n];
            float4 r;
            r.x = dn * a[0] + sbf[q * 4 + 0];
            r.y = dn * a[1] + sbf[q * 4 + 1];
            r.z = dn * a[2] + sbf[q * 4 + 2];
            r.w = dn * a[3] + sbf[q * 4 + 3];
            ((float4*)out)[(size_t)n * 4 + q] = r;
        }
    }
}

extern "C" void kernel_launch(void* const* d_in, const int* in_sizes, int n_in,
                              void* d_out, int out_size, void* d_ws, size_t ws_size,
                              hipStream_t stream) {
    const float* x  = (const float*)d_in[0];
    const int*   ei = (const int*)d_in[1];
    const float* W1 = (const float*)d_in[2];
    const float* b1 = (const float*)d_in[3];
    const float* W2 = (const float*)d_in[4];
    const float* b2 = (const float*)d_in[5];
    const float* WL = (const float*)d_in[6];
    const float* bL = (const float*)d_in[7];
    float* out = (float*)d_out;

    const int N  = in_sizes[0] / 16;       // 100000
    const int E  = in_sizes[1] / 2;        // 1600000
    const int C  = (N + RNG - 1) >> RSH;   // 782 ranges
    const int L  = C * 8;                  // (range, shard) cells
    const int NB = (E + EPB - 1) / EPB;    // 196 hist/place blocks

    // ws ints: gbuf[E] | bucketS[E] | ghist[L] | gbase[L+1] | gcur[L] | start[N+1] | pad
    //    then: dinv[N] f32 | Wf[1024] | bf[16] | pad16B | hsx[8N] half2 | z[8N] half2
    int* wsi        = (int*)d_ws;
    unsigned* gbuf  = (unsigned*)wsi;
    int* bucketS    = wsi + E;
    int* ghist      = bucketS + E;
    int* gbase      = ghist + L;
    int* gcur       = gbase + L + 1;
    int* start      = gcur + L;
    size_t off      = (size_t)2 * E + 3 * (size_t)L + 1 + (N + 1);
    off = (off + 3) & ~(size_t)3;
    float* dinv  = (float*)(wsi + off);
    float* Wf    = dinv + N;
    float* bf    = Wf + 1024;
    off = off + N + 1024 + 16;
    off = (off + 3) & ~(size_t)3;                 // 16B-align fp16 section
    __half2* hsx = (__half2*)(wsi + off);         // 8N half2
    __half2* z   = (__half2*)(wsi + off + (size_t)8 * N);

    // weight fusion + ghist zeroing (precedes k_hist in stream order)
    k_wfuse<<<4, TPB, 0, stream>>>(W2, WL, b2, bL, Wf, bf, ghist, L);

    // ---- phase A: counting sort by dst-range ----
    k_hist<<<NB, TPB, 0, stream>>>(ei, ghist, E, C);
    k_scan<<<1, TPB, 0, stream>>>(ghist, gbase, gcur, L);
    k_place<<<NB, TPB, 0, stream>>>(ei, gcur, gbuf, E, C);

    // ---- phase B: per-range node sort -> CSR + dinv + fp16 hsx ----
    k_sort2<<<C, TPB, 0, stream>>>(gbuf, gbase, x, bucketS, start, dinv, hsx, N, E);

    // ---- layer 1 + projection -> z fp16 [N,16] ----
    const int NBLK = (N + 15) / 16;               // 16 nodes per block (4/wave)
    k_l1f<<<NBLK, TPB, 0, stream>>>(bucketS, start, (const uint2*)hsx, W1, b1, Wf, dinv, z, N);

    // ---- layer 2 aggregation + bias -> out ----
    k_l3<<<NBLK, TPB, 0, stream>>>(bucketS, start, (const uint2*)z, bf, dinv, out, N);
}

// Round 12
// 190.602 us; speedup vs baseline: 1.4819x; 1.1580x over previous
//
#include <hip/hip_runtime.h>
#include <hip/hip_fp16.h>

#define TPB 256
#define RNG 128          // nodes per range
#define RSH 7            // log2(RNG)
#define MAXC 1024        // max ranges supported by LDS hist (N <= 131072)
#define EPB 8192         // edges per block in hist/place (chunk ~10.5 edges)

// ---------------------------------------------------------------------------
// GCN, fully commuted (aggregate only at width 16):
//   hsx = fp16(dinv*x) [N,16];  z = fp16((relu(dinv*agg@W1+b1)*dinv)@Wf) [N,16]
//   out = dinv*(z[n]+sum z[s]) + bf      (Wf = W2@WL, bf = b2@WL + bL)
// Build: R8-proven 2-phase counting sort (EPB=8192, int4 loads).
// Aggregation (R12): nodes-in-lane transpose gather — lane=(node,slot), each
// lane walks its own node's CSR list (no shfl tree; DS ops/node 84 -> ~12).
// k_l1f epilogue: weights in registers, agg/vrow via wide b128 LDS roundtrips.
// k_l3: pure gather + coalesced float4 store (zero DS).
// Replay-stable: fixed summation shape, no fp atomics (R9 tripwire lesson).
// ---------------------------------------------------------------------------

__device__ inline void acc4(float a[4], uint2 u) {
    __half2 h0 = *(__half2*)&u.x, h1 = *(__half2*)&u.y;
    float2 f0 = __half22float2(h0), f1 = __half22float2(h1);
    a[0] += f0.x; a[1] += f0.y; a[2] += f1.x; a[3] += f1.y;
}

// Wf/bf fusion + ghist zeroing (replaces memset dispatch)
__global__ void k_wfuse(const float* __restrict__ W2, const float* __restrict__ WL,
                        const float* __restrict__ b2, const float* __restrict__ bL,
                        float* __restrict__ Wf, float* __restrict__ bf,
                        int* __restrict__ ghist, int L) {
    int gid = blockIdx.x * TPB + threadIdx.x;     // 4 blocks * 256 = 1024
    for (int i = gid; i < L; i += 4 * TPB) ghist[i] = 0;
    int k = gid >> 4, o = gid & 15;
    if (k < 64) {
        float s = 0.f;
#pragma unroll 8
        for (int j = 0; j < 128; j++) s += W2[k * 128 + j] * WL[j * 16 + o];
        Wf[gid] = s;
    }
    if (gid < 16) {
        float s = bL[gid];
        for (int j = 0; j < 128; j++) s += b2[j] * WL[j * 16 + gid];
        bf[gid] = s;
    }
}

// per-block LDS histogram of dst-range (int4 loads), merged into ghist[c*8+j]
__global__ void k_hist(const int* __restrict__ ei, int* __restrict__ ghist,
                       int E, int C) {
    __shared__ int h[MAXC];
    int t = threadIdx.x, b = blockIdx.x, j = b & 7;
    for (int c = t; c < C; c += TPB) h[c] = 0;
    __syncthreads();
    const int4* d4p = (const int4*)(ei + E);
    int nq = E >> 2;
    int qbase = b * (EPB / 4);
    for (int it = 0; it < EPB / (4 * TPB); it++) {
        int q = qbase + it * TPB + t;
        if (q < nq) {
            int4 d = d4p[q];
            atomicAdd(&h[d.x >> RSH], 1);
            atomicAdd(&h[d.y >> RSH], 1);
            atomicAdd(&h[d.z >> RSH], 1);
            atomicAdd(&h[d.w >> RSH], 1);
        }
    }
    __syncthreads();
    for (int c = t; c < C; c += TPB) {
        int v = h[c];
        if (v) atomicAdd(&ghist[c * 8 + j], v);
    }
}

// single-block exclusive scan of ghist[0..L) -> gbase (+sentinel), gcur copy
__global__ void k_scan(const int* __restrict__ ghist, int* __restrict__ gbase,
                       int* __restrict__ gcur, int L) {
    __shared__ int ssum[TPB];
    int t = threadIdx.x;
    int CH = (L + TPB - 1) / TPB;
    int lo = t * CH, hi = min(L, lo + CH);
    int s = 0;
    for (int i = lo; i < hi; i++) s += ghist[i];
    ssum[t] = s;
    __syncthreads();
    for (int off = 1; off < TPB; off <<= 1) {
        int v = (t >= off) ? ssum[t - off] : 0;
        __syncthreads();
        ssum[t] += v;
        __syncthreads();
    }
    int base = (t == 0) ? 0 : ssum[t - 1];
    for (int i = lo; i < hi; i++) { gbase[i] = base; gcur[i] = base; base += ghist[i]; }
    if (t == TPB - 1) gbase[L] = base;            // = E
}

// place packed (src<<7 | dst&127) into range-sorted gbuf; chunk reservation
__global__ void k_place(const int* __restrict__ ei, int* __restrict__ gcur,
                        unsigned* __restrict__ gbuf, int E, int C) {
    __shared__ int h[MAXC];
    int t = threadIdx.x, b = blockIdx.x, j = b & 7;
    for (int c = t; c < C; c += TPB) h[c] = 0;
    __syncthreads();
    const int4* s4p = (const int4*)ei;
    const int4* d4p = (const int4*)(ei + E);
    int nq = E >> 2;
    int qbase = b * (EPB / 4);
    for (int it = 0; it < EPB / (4 * TPB); it++) {  // pass 1: count
        int q = qbase + it * TPB + t;
        if (q < nq) {
            int4 d = d4p[q];
            atomicAdd(&h[d.x >> RSH], 1);
            atomicAdd(&h[d.y >> RSH], 1);
            atomicAdd(&h[d.z >> RSH], 1);
            atomicAdd(&h[d.w >> RSH], 1);
        }
    }
    __syncthreads();
    for (int c = t; c < C; c += TPB) {            // reserve chunk per (c, shard)
        int v = h[c];
        if (v) h[c] = atomicAdd(&gcur[c * 8 + j], v);
    }
    __syncthreads();
    for (int it = 0; it < EPB / (4 * TPB); it++) {  // pass 2: chunked place
        int q = qbase + it * TPB + t;
        if (q < nq) {
            int4 s = s4p[q];
            int4 d = d4p[q];
            int p0 = atomicAdd(&h[d.x >> RSH], 1);
            gbuf[p0] = ((unsigned)s.x << RSH) | (unsigned)(d.x & (RNG - 1));
            int p1 = atomicAdd(&h[d.y >> RSH], 1);
            gbuf[p1] = ((unsigned)s.y << RSH) | (unsigned)(d.y & (RNG - 1));
            int p2 = atomicAdd(&h[d.z >> RSH], 1);
            gbuf[p2] = ((unsigned)s.z << RSH) | (unsigned)(d.z & (RNG - 1));
            int p3 = atomicAdd(&h[d.w >> RSH], 1);
            gbuf[p3] = ((unsigned)s.w << RSH) | (unsigned)(d.w & (RNG - 1));
        }
    }
}

// per-range node-sort -> bucketS/start/dinv; fused hsx = fp16(dinv*x)
__global__ void k_sort2(const unsigned* __restrict__ gbuf, const int* __restrict__ gbase,
                        const float* __restrict__ x,
                        int* __restrict__ bucketS, int* __restrict__ start,
                        float* __restrict__ dinv, __half2* __restrict__ hsx,
                        int N, int E) {
    __shared__ int cnt[RNG];
    __shared__ int offs[RNG];
    __shared__ int cur[RNG];
    __shared__ float sdi[RNG];
    int t = threadIdx.x, r = blockIdx.x;
    if (t < RNG) cnt[t] = 0;
    __syncthreads();
    int lo = gbase[r * 8], hi = gbase[r * 8 + 8];
    for (int i = lo + t; i < hi; i += TPB)
        atomicAdd(&cnt[gbuf[i] & (RNG - 1)], 1);
    __syncthreads();
    if (t < RNG) offs[t] = cnt[t];
    __syncthreads();
    for (int off = 1; off < RNG; off <<= 1) {     // Hillis-Steele inclusive scan
        int v = 0;
        if (t < RNG && t >= off) v = offs[t - off];
        __syncthreads();
        if (t < RNG) offs[t] += v;
        __syncthreads();
    }
    if (t < RNG) {
        int ex = offs[t] - cnt[t];                // exclusive
        cur[t] = ex;
        float di = rsqrtf((float)cnt[t] + 1.0f);  // +1 self-loop
        sdi[t] = di;
        int n = r * RNG + t;
        if (n < N) { start[n] = lo + ex; dinv[n] = di; }
    }
    if (r == 0 && t == 0) start[N] = E;           // CSR sentinel
    __syncthreads();
    for (int i = lo + t; i < hi; i += TPB) {
        unsigned p = gbuf[i];
        int pos = lo + atomicAdd(&cur[p & (RNG - 1)], 1);
        bucketS[pos] = (int)(p >> RSH);
    }
    // fused: hsx[n][:] = fp16(dinv[n] * x[n][:]) — 128 nodes x 8 half2
    for (int idx = t; idx < RNG * 8; idx += TPB) {
        int ln = idx >> 3, f2 = idx & 7;
        int n = r * RNG + ln;
        if (n < N) {
            float2 xv = ((const float2*)x)[(size_t)n * 8 + f2];
            float dn = sdi[ln];
            hsx[(size_t)n * 8 + f2] = __floats2half2_rn(xv.x * dn, xv.y * dn);
        }
    }
}

// layer 1 + projection: nodes-in-lane gather (16 nodes/wave), register weights
__global__ void k_l1f(const int* __restrict__ bucketS, const int* __restrict__ start,
                      const uint2* __restrict__ hsx, const float* __restrict__ W1,
                      const float* __restrict__ b1, const float* __restrict__ Wf,
                      const float* __restrict__ dinv, __half2* __restrict__ z, int N) {
    __shared__ __align__(16) float agg[4][16][16];   // [wave][node][feat]
    __shared__ __align__(16) float vrow[4][64];
    int t = threadIdx.x, wid = t >> 6, lane = t & 63;
    int part = lane >> 4, o = lane & 15;
    // register weights: lane j holds W1[:,j]; lane (part,o) holds Wf[part*16+j][o]
    float w1c[16], wfc[16];
#pragma unroll
    for (int k = 0; k < 16; k++) w1c[k] = W1[k * 64 + lane];
#pragma unroll
    for (int j = 0; j < 16; j++) wfc[j] = Wf[(part * 16 + j) * 16 + o];
    float b1v = b1[lane];
    int nodeG = (blockIdx.x * 4 + wid) * 16;      // 16 nodes per wave
    // gather: lane (n4,q) owns node nodeG+n4, slot q (8B of the 32B row)
    int n4 = lane >> 2, q = lane & 3;
    int n = nodeG + n4;
    bool valid = n < N;
    int base = 0, d = 0;
    if (valid) { base = start[n]; d = start[n + 1] - base; }
    float a[4] = {0.f, 0.f, 0.f, 0.f};
    if (valid) acc4(a, hsx[(size_t)n * 4 + q]);   // self-loop
    int k = 0;
    for (; k + 1 < d; k += 2) {                   // 2 chains/lane, 32/wave
        int s0 = bucketS[base + k];
        int s1 = bucketS[base + k + 1];
        uint2 u0 = hsx[(size_t)s0 * 4 + q];
        uint2 u1 = hsx[(size_t)s1 * 4 + q];
        acc4(a, u0);
        acc4(a, u1);
    }
    if (k < d) acc4(a, hsx[(size_t)bucketS[base + k] * 4 + q]);
    *(float4*)&agg[wid][n4][q * 4] = make_float4(a[0], a[1], a[2], a[3]);
    // dinv for the wave's 16 nodes, one per low lane
    float dval = dinv[min(nodeG + o, N - 1)];
    // epilogue: 16 nodes batched; agg/vrow same-wave LDS roundtrips (b128)
    const float4* avp = (const float4*)agg[wid];
    const float4* vrp = (const float4*)vrow[wid];
#pragma unroll 4
    for (int nn = 0; nn < 16; nn++) {
        int node = nodeG + nn;
        if (node >= N) break;                     // wave-uniform
        float dn = __shfl(dval, nn);
        float4 A0 = avp[nn * 4 + 0], A1 = avp[nn * 4 + 1];
        float4 A2 = avp[nn * 4 + 2], A3 = avp[nn * 4 + 3];
        float av[16] = {A0.x, A0.y, A0.z, A0.w, A1.x, A1.y, A1.z, A1.w,
                        A2.x, A2.y, A2.z, A2.w, A3.x, A3.y, A3.z, A3.w};
        float v = 0.f;
#pragma unroll
        for (int kk = 0; kk < 16; kk++) v += av[kk] * w1c[kk];
        v = fmaxf(dn * v + b1v, 0.f) * dn;        // lane j holds v_j
        vrow[wid][lane] = v;
        float4 V0 = vrp[part * 4 + 0], V1 = vrp[part * 4 + 1];
        float4 V2 = vrp[part * 4 + 2], V3 = vrp[part * 4 + 3];
        float vv[16] = {V0.x, V0.y, V0.z, V0.w, V1.x, V1.y, V1.z, V1.w,
                        V2.x, V2.y, V2.z, V2.w, V3.x, V3.y, V3.z, V3.w};
        float s = 0.f;
#pragma unroll
        for (int j = 0; j < 16; j++) s += vv[j] * wfc[j];
        s += __shfl_xor(s, 16);
        s += __shfl_xor(s, 32);                   // all lanes: z_o, o=lane&15
        float pv = __shfl(s, lane | 1);
        if (part == 0 && !(lane & 1))
            z[(size_t)node * 8 + (o >> 1)] = __floats2half2_rn(s, pv);
    }
}

// layer 2 aggregation of z + bias: pure nodes-in-lane gather, zero DS ops
__global__ void k_l3(const int* __restrict__ bucketS, const int* __restrict__ start,
                     const uint2* __restrict__ z, const float* __restrict__ bfv,
                     const float* __restrict__ dinv, float* __restrict__ out, int N) {
    int t = threadIdx.x, wid = t >> 6, lane = t & 63;
    int n4 = lane >> 2, q = lane & 3;
    int n = (blockIdx.x * 4 + wid) * 16 + n4;
    if (n >= N) return;
    float4 bq = ((const float4*)bfv)[q];
    int base = start[n], d = start[n + 1] - base;
    float a[4] = {0.f, 0.f, 0.f, 0.f};
    acc4(a, z[(size_t)n * 4 + q]);                // self-loop
    int k = 0;
    for (; k + 1 < d; k += 2) {
        int s0 = bucketS[base + k];
        int s1 = bucketS[base + k + 1];
        uint2 u0 = z[(size_t)s0 * 4 + q];
        uint2 u1 = z[(size_t)s1 * 4 + q];
        acc4(a, u0);
        acc4(a, u1);
    }
    if (k < d) acc4(a, z[(size_t)bucketS[base + k] * 4 + q]);
    float dn = dinv[n];
    float4 r;
    r.x = dn * a[0] + bq.x;
    r.y = dn * a[1] + bq.y;
    r.z = dn * a[2] + bq.z;
    r.w = dn * a[3] + bq.w;
    ((float4*)out)[(size_t)n * 4 + q] = r;        // fully coalesced
}

extern "C" void kernel_launch(void* const* d_in, const int* in_sizes, int n_in,
                              void* d_out, int out_size, void* d_ws, size_t ws_size,
                              hipStream_t stream) {
    const float* x  = (const float*)d_in[0];
    const int*   ei = (const int*)d_in[1];
    const float* W1 = (const float*)d_in[2];
    const float* b1 = (const float*)d_in[3];
    const float* W2 = (const float*)d_in[4];
    const float* b2 = (const float*)d_in[5];
    const float* WL = (const float*)d_in[6];
    const float* bL = (const float*)d_in[7];
    float* out = (float*)d_out;

    const int N  = in_sizes[0] / 16;       // 100000
    const int E  = in_sizes[1] / 2;        // 1600000
    const int C  = (N + RNG - 1) >> RSH;   // 782 ranges
    const int L  = C * 8;                  // (range, shard) cells
    const int NB = (E + EPB - 1) / EPB;    // 196 hist/place blocks

    // ws ints: gbuf[E] | bucketS[E] | ghist[L] | gbase[L+1] | gcur[L] | start[N+1] | pad
    //    then: dinv[N] f32 | Wf[1024] | bf[16] | pad16B | hsx[8N] half2 | z[8N] half2
    int* wsi        = (int*)d_ws;
    unsigned* gbuf  = (unsigned*)wsi;
    int* bucketS    = wsi + E;
    int* ghist      = bucketS + E;
    int* gbase      = ghist + L;
    int* gcur       = gbase + L + 1;
    int* start      = gcur + L;
    size_t off      = (size_t)2 * E + 3 * (size_t)L + 1 + (N + 1);
    off = (off + 3) & ~(size_t)3;
    float* dinv  = (float*)(wsi + off);
    float* Wf    = dinv + N;
    float* bf    = Wf + 1024;
    off = off + N + 1024 + 16;
    off = (off + 3) & ~(size_t)3;                 // 16B-align fp16 section
    __half2* hsx = (__half2*)(wsi + off);         // 8N half2
    __half2* z   = (__half2*)(wsi + off + (size_t)8 * N);

    // weight fusion + ghist zeroing (precedes k_hist in stream order)
    k_wfuse<<<4, TPB, 0, stream>>>(W2, WL, b2, bL, Wf, bf, ghist, L);

    // ---- phase A: counting sort by dst-range ----
    k_hist<<<NB, TPB, 0, stream>>>(ei, ghist, E, C);
    k_scan<<<1, TPB, 0, stream>>>(ghist, gbase, gcur, L);
    k_place<<<NB, TPB, 0, stream>>>(ei, gcur, gbuf, E, C);

    // ---- phase B: per-range node sort -> CSR + dinv + fp16 hsx ----
    k_sort2<<<C, TPB, 0, stream>>>(gbuf, gbase, x, bucketS, start, dinv, hsx, N, E);

    // ---- layer 1 + projection -> z fp16 [N,16] ----
    const int NBLK = (N + 63) / 64;               // 64 nodes per block (16/wave)
    k_l1f<<<NBLK, TPB, 0, stream>>>(bucketS, start, (const uint2*)hsx, W1, b1, Wf, dinv, z, N);

    // ---- layer 2 aggregation + bias -> out ----
    k_l3<<<NBLK, TPB, 0, stream>>>(bucketS, start, (const uint2*)z, bf, dinv, out, N);
}

// Round 13
// 164.257 us; speedup vs baseline: 1.7195x; 1.1604x over previous
//
#include <hip/hip_runtime.h>
#include <hip/hip_fp16.h>

#define TPB 256
#define RNG 128          // nodes per range
#define RSH 7            // log2(RNG)
#define MAXC 1024        // max ranges supported by LDS hist (N <= 131072)
#define EPB 8192         // edges per block in place (chunk ~10.5 edges)
#define CAPR 4096        // per-range region capacity (mean ~2046, ~40 sigma)
#define CSH 12           // log2(CAPR)

// ---------------------------------------------------------------------------
// GCN, fully commuted (aggregate only at width 16):
//   hsx = fp16(dinv*x) [N,16];  z = fp16((relu(dinv*agg@W1+b1)*dinv)@Wf) [N,16]
//   out = dinv*(z[n]+sum z[s]) + bf      (Wf = W2@WL, bf = b2@WL + bL)
// Build (R13): fixed-capacity per-range regions -> NO global hist/scan pass.
//   place: per-block LDS count -> one atomicAdd(&gcur[c],v) chunk reservation
//          per (block,range) -> chunked packed writes into gbuf[c*4096+..]
//   sort2: region -> LDS elist (single global read) -> per-node sort ->
//          bucketS[c*4096+..], pack[n]=(exoff<<16)|deg, dinv, fp16 hsx
// Aggregation: nodes-in-lane transpose gather (R12-proven), 1-load packed CSR.
// Replay-stable: fixed summation shape, no fp atomics (R9 tripwire lesson).
// ---------------------------------------------------------------------------

__device__ inline void acc4(float a[4], uint2 u) {
    __half2 h0 = *(__half2*)&u.x, h1 = *(__half2*)&u.y;
    float2 f0 = __half22float2(h0), f1 = __half22float2(h1);
    a[0] += f0.x; a[1] += f0.y; a[2] += f1.x; a[3] += f1.y;
}

// Wf/bf fusion + gcur zeroing (replaces memset dispatch)
__global__ void k_wfuse(const float* __restrict__ W2, const float* __restrict__ WL,
                        const float* __restrict__ b2, const float* __restrict__ bL,
                        float* __restrict__ Wf, float* __restrict__ bf,
                        int* __restrict__ gcur, int C) {
    int gid = blockIdx.x * TPB + threadIdx.x;     // 4 blocks * 256 = 1024
    for (int i = gid; i < C; i += 4 * TPB) gcur[i] = 0;
    int k = gid >> 4, o = gid & 15;
    if (k < 64) {
        float s = 0.f;
#pragma unroll 8
        for (int j = 0; j < 128; j++) s += W2[k * 128 + j] * WL[j * 16 + o];
        Wf[gid] = s;
    }
    if (gid < 16) {
        float s = bL[gid];
        for (int j = 0; j < 128; j++) s += b2[j] * WL[j * 16 + gid];
        bf[gid] = s;
    }
}

// place packed (src<<7 | dst&127) into per-range fixed regions; chunk reservation
__global__ void k_place(const int* __restrict__ ei, int* __restrict__ gcur,
                        unsigned* __restrict__ gbuf, int E, int C) {
    __shared__ int h[MAXC];
    int t = threadIdx.x, b = blockIdx.x;
    for (int c = t; c < C; c += TPB) h[c] = 0;
    __syncthreads();
    const int4* s4p = (const int4*)ei;
    const int4* d4p = (const int4*)(ei + E);
    int nq = E >> 2;
    int qbase = b * (EPB / 4);
    for (int it = 0; it < EPB / (4 * TPB); it++) {  // pass 1: count
        int q = qbase + it * TPB + t;
        if (q < nq) {
            int4 d = d4p[q];
            atomicAdd(&h[d.x >> RSH], 1);
            atomicAdd(&h[d.y >> RSH], 1);
            atomicAdd(&h[d.z >> RSH], 1);
            atomicAdd(&h[d.w >> RSH], 1);
        }
    }
    __syncthreads();
    for (int c = t; c < C; c += TPB) {            // reserve chunk per range
        int v = h[c];
        if (v) h[c] = (c << CSH) + atomicAdd(&gcur[c], v);   // absolute cursor
    }
    __syncthreads();
    for (int it = 0; it < EPB / (4 * TPB); it++) {  // pass 2: chunked place
        int q = qbase + it * TPB + t;
        if (q < nq) {
            int4 s = s4p[q];
            int4 d = d4p[q];
            int c0 = d.x >> RSH, c1 = d.y >> RSH, c2 = d.z >> RSH, c3 = d.w >> RSH;
            int p0 = atomicAdd(&h[c0], 1);
            if (p0 < ((c0 + 1) << CSH))
                gbuf[p0] = ((unsigned)s.x << RSH) | (unsigned)(d.x & (RNG - 1));
            int p1 = atomicAdd(&h[c1], 1);
            if (p1 < ((c1 + 1) << CSH))
                gbuf[p1] = ((unsigned)s.y << RSH) | (unsigned)(d.y & (RNG - 1));
            int p2 = atomicAdd(&h[c2], 1);
            if (p2 < ((c2 + 1) << CSH))
                gbuf[p2] = ((unsigned)s.z << RSH) | (unsigned)(d.z & (RNG - 1));
            int p3 = atomicAdd(&h[c3], 1);
            if (p3 < ((c3 + 1) << CSH))
                gbuf[p3] = ((unsigned)s.w << RSH) | (unsigned)(d.w & (RNG - 1));
        }
    }
}

// per-range node-sort (via LDS elist) -> bucketS region + packed CSR + dinv + hsx
__global__ void k_sort2(const unsigned* __restrict__ gbuf, const int* __restrict__ gcur,
                        const float* __restrict__ x,
                        int* __restrict__ bucketS, unsigned* __restrict__ pack,
                        float* __restrict__ dinv, __half2* __restrict__ hsx,
                        int N, int C) {
    __shared__ unsigned elist[CAPR];              // 16 KiB
    __shared__ int cnt[RNG];
    __shared__ int offs[RNG];
    __shared__ int cur[RNG];
    __shared__ float sdi[RNG];
    int t = threadIdx.x, r = blockIdx.x;
    if (t < RNG) cnt[t] = 0;
    __syncthreads();
    int m = min(gcur[r], CAPR);
    const unsigned* src = gbuf + ((size_t)r << CSH);
    for (int i = t; i < m; i += TPB) {            // single global read of region
        unsigned p = src[i];
        elist[i] = p;
        atomicAdd(&cnt[p & (RNG - 1)], 1);
    }
    __syncthreads();
    if (t < RNG) offs[t] = cnt[t];
    __syncthreads();
    for (int off = 1; off < RNG; off <<= 1) {     // Hillis-Steele inclusive scan
        int v = 0;
        if (t < RNG && t >= off) v = offs[t - off];
        __syncthreads();
        if (t < RNG) offs[t] += v;
        __syncthreads();
    }
    if (t < RNG) {
        int ex = offs[t] - cnt[t];                // exclusive
        cur[t] = ex;
        float di = rsqrtf((float)cnt[t] + 1.0f);  // +1 self-loop
        sdi[t] = di;
        int n = r * RNG + t;
        if (n < N) {
            pack[n] = ((unsigned)ex << 16) | (unsigned)cnt[t];
            dinv[n] = di;
        }
    }
    __syncthreads();
    int rbase = r << CSH;
    for (int i = t; i < m; i += TPB) {
        unsigned p = elist[i];
        int pos = rbase + atomicAdd(&cur[p & (RNG - 1)], 1);
        bucketS[pos] = (int)(p >> RSH);
    }
    // fused: hsx[n][:] = fp16(dinv[n] * x[n][:]) — 128 nodes x 8 half2
    for (int idx = t; idx < RNG * 8; idx += TPB) {
        int ln = idx >> 3, f2 = idx & 7;
        int n = r * RNG + ln;
        if (n < N) {
            float2 xv = ((const float2*)x)[(size_t)n * 8 + f2];
            float dn = sdi[ln];
            hsx[(size_t)n * 8 + f2] = __floats2half2_rn(xv.x * dn, xv.y * dn);
        }
    }
}

// layer 1 + projection: nodes-in-lane gather (16 nodes/wave), register weights
__global__ void k_l1f(const int* __restrict__ bucketS, const unsigned* __restrict__ pack,
                      const uint2* __restrict__ hsx, const float* __restrict__ W1,
                      const float* __restrict__ b1, const float* __restrict__ Wf,
                      const float* __restrict__ dinv, __half2* __restrict__ z, int N) {
    __shared__ __align__(16) float agg[4][16][16];   // [wave][node][feat]
    __shared__ __align__(16) float vrow[4][64];
    int t = threadIdx.x, wid = t >> 6, lane = t & 63;
    int part = lane >> 4, o = lane & 15;
    // register weights: lane j holds W1[:,j]; lane (part,o) holds Wf[part*16+j][o]
    float w1c[16], wfc[16];
#pragma unroll
    for (int k = 0; k < 16; k++) w1c[k] = W1[k * 64 + lane];
#pragma unroll
    for (int j = 0; j < 16; j++) wfc[j] = Wf[(part * 16 + j) * 16 + o];
    float b1v = b1[lane];
    int nodeG = (blockIdx.x * 4 + wid) * 16;      // 16 nodes per wave
    // gather: lane (n4,q) owns node nodeG+n4, slot q (8B of the 32B row)
    int n4 = lane >> 2, q = lane & 3;
    int n = nodeG + n4;
    bool valid = n < N;
    int base = 0, d = 0;
    if (valid) {
        unsigned p = pack[n];
        base = ((n >> RSH) << CSH) + (int)(p >> 16);
        d = (int)(p & 0xFFFF);
    }
    float a[4] = {0.f, 0.f, 0.f, 0.f};
    if (valid) acc4(a, hsx[(size_t)n * 4 + q]);   // self-loop
    int k = 0;
    for (; k + 1 < d; k += 2) {                   // 2 chains/lane, 32/wave
        int s0 = bucketS[base + k];
        int s1 = bucketS[base + k + 1];
        uint2 u0 = hsx[(size_t)s0 * 4 + q];
        uint2 u1 = hsx[(size_t)s1 * 4 + q];
        acc4(a, u0);
        acc4(a, u1);
    }
    if (k < d) acc4(a, hsx[(size_t)bucketS[base + k] * 4 + q]);
    *(float4*)&agg[wid][n4][q * 4] = make_float4(a[0], a[1], a[2], a[3]);
    // dinv for the wave's 16 nodes, one per low lane
    float dval = dinv[min(nodeG + o, N - 1)];
    // epilogue: 16 nodes batched; agg/vrow same-wave LDS roundtrips (b128)
    const float4* avp = (const float4*)agg[wid];
    const float4* vrp = (const float4*)vrow[wid];
#pragma unroll 4
    for (int nn = 0; nn < 16; nn++) {
        int node = nodeG + nn;
        if (node >= N) break;                     // wave-uniform
        float dn = __shfl(dval, nn);
        float4 A0 = avp[nn * 4 + 0], A1 = avp[nn * 4 + 1];
        float4 A2 = avp[nn * 4 + 2], A3 = avp[nn * 4 + 3];
        float av[16] = {A0.x, A0.y, A0.z, A0.w, A1.x, A1.y, A1.z, A1.w,
                        A2.x, A2.y, A2.z, A2.w, A3.x, A3.y, A3.z, A3.w};
        float v = 0.f;
#pragma unroll
        for (int kk = 0; kk < 16; kk++) v += av[kk] * w1c[kk];
        v = fmaxf(dn * v + b1v, 0.f) * dn;        // lane j holds v_j
        vrow[wid][lane] = v;
        float4 V0 = vrp[part * 4 + 0], V1 = vrp[part * 4 + 1];
        float4 V2 = vrp[part * 4 + 2], V3 = vrp[part * 4 + 3];
        float vv[16] = {V0.x, V0.y, V0.z, V0.w, V1.x, V1.y, V1.z, V1.w,
                        V2.x, V2.y, V2.z, V2.w, V3.x, V3.y, V3.z, V3.w};
        float s = 0.f;
#pragma unroll
        for (int j = 0; j < 16; j++) s += vv[j] * wfc[j];
        s += __shfl_xor(s, 16);
        s += __shfl_xor(s, 32);                   // all lanes: z_o, o=lane&15
        float pv = __shfl(s, lane | 1);
        if (part == 0 && !(lane & 1))
            z[(size_t)node * 8 + (o >> 1)] = __floats2half2_rn(s, pv);
    }
}

// layer 2 aggregation of z + bias: pure nodes-in-lane gather, zero DS ops
__global__ void k_l3(const int* __restrict__ bucketS, const unsigned* __restrict__ pack,
                     const uint2* __restrict__ z, const float* __restrict__ bfv,
                     const float* __restrict__ dinv, float* __restrict__ out, int N) {
    int t = threadIdx.x, wid = t >> 6, lane = t & 63;
    int n4 = lane >> 2, q = lane & 3;
    int n = (blockIdx.x * 4 + wid) * 16 + n4;
    if (n >= N) return;
    float4 bq = ((const float4*)bfv)[q];
    unsigned p = pack[n];
    int base = ((n >> RSH) << CSH) + (int)(p >> 16);
    int d = (int)(p & 0xFFFF);
    float a[4] = {0.f, 0.f, 0.f, 0.f};
    acc4(a, z[(size_t)n * 4 + q]);                // self-loop
    int k = 0;
    for (; k + 1 < d; k += 2) {
        int s0 = bucketS[base + k];
        int s1 = bucketS[base + k + 1];
        uint2 u0 = z[(size_t)s0 * 4 + q];
        uint2 u1 = z[(size_t)s1 * 4 + q];
        acc4(a, u0);
        acc4(a, u1);
    }
    if (k < d) acc4(a, z[(size_t)bucketS[base + k] * 4 + q]);
    float dn = dinv[n];
    float4 r;
    r.x = dn * a[0] + bq.x;
    r.y = dn * a[1] + bq.y;
    r.z = dn * a[2] + bq.z;
    r.w = dn * a[3] + bq.w;
    ((float4*)out)[(size_t)n * 4 + q] = r;        // fully coalesced
}

extern "C" void kernel_launch(void* const* d_in, const int* in_sizes, int n_in,
                              void* d_out, int out_size, void* d_ws, size_t ws_size,
                              hipStream_t stream) {
    const float* x  = (const float*)d_in[0];
    const int*   ei = (const int*)d_in[1];
    const float* W1 = (const float*)d_in[2];
    const float* b1 = (const float*)d_in[3];
    const float* W2 = (const float*)d_in[4];
    const float* b2 = (const float*)d_in[5];
    const float* WL = (const float*)d_in[6];
    const float* bL = (const float*)d_in[7];
    float* out = (float*)d_out;

    const int N  = in_sizes[0] / 16;       // 100000
    const int E  = in_sizes[1] / 2;        // 1600000
    const int C  = (N + RNG - 1) >> RSH;   // 782 ranges
    const int NB = (E + EPB - 1) / EPB;    // 196 place blocks

    // ws ints: gbuf[C*CAPR] | bucketS[C*CAPR] | gcur[C] | pack[N] | pad
    //    then: dinv[N] f32 | Wf[1024] | bf[16] | pad16B | hsx[8N] half2 | z[8N] half2
    int* wsi        = (int*)d_ws;
    unsigned* gbuf  = (unsigned*)wsi;
    int* bucketS    = wsi + ((size_t)C << CSH);
    int* gcur       = bucketS + ((size_t)C << CSH);
    unsigned* pack  = (unsigned*)(gcur + C);
    size_t off      = ((size_t)C << (CSH + 1)) + C + N;
    off = (off + 3) & ~(size_t)3;
    float* dinv  = (float*)(wsi + off);
    float* Wf    = dinv + N;
    float* bf    = Wf + 1024;
    off = off + N + 1024 + 16;
    off = (off + 3) & ~(size_t)3;                 // 16B-align fp16 section
    __half2* hsx = (__half2*)(wsi + off);         // 8N half2
    __half2* z   = (__half2*)(wsi + off + (size_t)8 * N);

    // weight fusion + gcur zeroing (precedes k_place in stream order)
    k_wfuse<<<4, TPB, 0, stream>>>(W2, WL, b2, bL, Wf, bf, gcur, C);

    // ---- single-pass chunked placement into per-range regions ----
    k_place<<<NB, TPB, 0, stream>>>(ei, gcur, gbuf, E, C);

    // ---- per-range node sort -> region CSR + pack + dinv + fp16 hsx ----
    k_sort2<<<C, TPB, 0, stream>>>(gbuf, gcur, x, bucketS, pack, dinv, hsx, N, C);

    // ---- layer 1 + projection -> z fp16 [N,16] ----
    const int NBLK = (N + 63) / 64;               // 64 nodes per block (16/wave)
    k_l1f<<<NBLK, TPB, 0, stream>>>(bucketS, pack, (const uint2*)hsx, W1, b1, Wf, dinv, z, N);

    // ---- layer 2 aggregation + bias -> out ----
    k_l3<<<NBLK, TPB, 0, stream>>>(bucketS, pack, (const uint2*)z, bf, dinv, out, N);
}

// Round 14
// 160.653 us; speedup vs baseline: 1.7581x; 1.0224x over previous
//
#include <hip/hip_runtime.h>
#include <hip/hip_fp16.h>

#define TPB 256
#define TPBP 1024        // k_place block (16 waves -> latency hiding)
#define TPBS 512         // k_sort2 block
#define RNG 128          // nodes per range
#define RSH 7            // log2(RNG)
#define MAXC 1024        // max ranges supported by LDS hist (N <= 131072)
#define EPB 8192         // edges per block in place (chunk ~10.5 edges)
#define CAPR 4096        // per-range region capacity (mean ~2046, ~40 sigma)
#define CSH 12           // log2(CAPR)

// ---------------------------------------------------------------------------
// GCN, fully commuted (aggregate only at width 16):
//   hsx = fp16(dinv*x) [N,16];  z = fp16((relu(dinv*agg@W1+b1)*dinv)@Wf) [N,16]
//   out = dinv*(z[n]+sum z[s]) + bf      (Wf = W2@WL, bf = b2@WL + bL)
// Build: fixed-capacity per-range regions (no global hist/scan):
//   place (1024 thr): LDS count -> one atomicAdd(&gcur[c],v) chunk reservation
//          per (block,range) -> chunked packed writes into gbuf[c*4096+..]
//   sort2 (512 thr): region -> LDS elist -> per-node sort -> bucketS region,
//          pack[n]=(exoff<<16)|deg, fp16 hsx.  dinv recomputed from deg later.
// Aggregation: nodes-in-lane transpose gather (R12-proven), 1-load packed CSR.
// Replay-stable: fixed summation shape, no fp atomics (R9 tripwire lesson).
// ---------------------------------------------------------------------------

__device__ inline void acc4(float a[4], uint2 u) {
    __half2 h0 = *(__half2*)&u.x, h1 = *(__half2*)&u.y;
    float2 f0 = __half22float2(h0), f1 = __half22float2(h1);
    a[0] += f0.x; a[1] += f0.y; a[2] += f1.x; a[3] += f1.y;
}

// Wf/bf fusion + gcur zeroing (replaces memset dispatch)
__global__ void k_wfuse(const float* __restrict__ W2, const float* __restrict__ WL,
                        const float* __restrict__ b2, const float* __restrict__ bL,
                        float* __restrict__ Wf, float* __restrict__ bf,
                        int* __restrict__ gcur, int C) {
    int gid = blockIdx.x * TPB + threadIdx.x;     // 4 blocks * 256 = 1024
    for (int i = gid; i < C; i += 4 * TPB) gcur[i] = 0;
    int k = gid >> 4, o = gid & 15;
    if (k < 64) {
        float s = 0.f;
#pragma unroll 8
        for (int j = 0; j < 128; j++) s += W2[k * 128 + j] * WL[j * 16 + o];
        Wf[gid] = s;
    }
    if (gid < 16) {
        float s = bL[gid];
        for (int j = 0; j < 128; j++) s += b2[j] * WL[j * 16 + gid];
        bf[gid] = s;
    }
}

// place packed (src<<7 | dst&127) into per-range fixed regions; chunk reservation
__global__ __launch_bounds__(TPBP) void
k_place(const int* __restrict__ ei, int* __restrict__ gcur,
        unsigned* __restrict__ gbuf, int E, int C) {
    __shared__ int h[MAXC];
    int t = threadIdx.x, b = blockIdx.x;
    for (int c = t; c < C; c += TPBP) h[c] = 0;
    __syncthreads();
    const int4* s4p = (const int4*)ei;
    const int4* d4p = (const int4*)(ei + E);
    int nq = E >> 2;
    int qbase = b * (EPB / 4);
#pragma unroll
    for (int it = 0; it < EPB / (4 * TPBP); it++) {  // pass 1: count
        int q = qbase + it * TPBP + t;
        if (q < nq) {
            int4 d = d4p[q];
            atomicAdd(&h[d.x >> RSH], 1);
            atomicAdd(&h[d.y >> RSH], 1);
            atomicAdd(&h[d.z >> RSH], 1);
            atomicAdd(&h[d.w >> RSH], 1);
        }
    }
    __syncthreads();
    for (int c = t; c < C; c += TPBP) {           // reserve chunk per range
        int v = h[c];
        if (v) h[c] = (c << CSH) + atomicAdd(&gcur[c], v);   // absolute cursor
    }
    __syncthreads();
#pragma unroll
    for (int it = 0; it < EPB / (4 * TPBP); it++) {  // pass 2: chunked place
        int q = qbase + it * TPBP + t;
        if (q < nq) {
            int4 s = s4p[q];
            int4 d = d4p[q];
            int c0 = d.x >> RSH, c1 = d.y >> RSH, c2 = d.z >> RSH, c3 = d.w >> RSH;
            int p0 = atomicAdd(&h[c0], 1);
            if (p0 < ((c0 + 1) << CSH))
                gbuf[p0] = ((unsigned)s.x << RSH) | (unsigned)(d.x & (RNG - 1));
            int p1 = atomicAdd(&h[c1], 1);
            if (p1 < ((c1 + 1) << CSH))
                gbuf[p1] = ((unsigned)s.y << RSH) | (unsigned)(d.y & (RNG - 1));
            int p2 = atomicAdd(&h[c2], 1);
            if (p2 < ((c2 + 1) << CSH))
                gbuf[p2] = ((unsigned)s.z << RSH) | (unsigned)(d.z & (RNG - 1));
            int p3 = atomicAdd(&h[c3], 1);
            if (p3 < ((c3 + 1) << CSH))
                gbuf[p3] = ((unsigned)s.w << RSH) | (unsigned)(d.w & (RNG - 1));
        }
    }
}

// per-range node-sort (via LDS elist) -> bucketS region + packed CSR + hsx
__global__ __launch_bounds__(TPBS) void
k_sort2(const unsigned* __restrict__ gbuf, const int* __restrict__ gcur,
        const float* __restrict__ x,
        int* __restrict__ bucketS, unsigned* __restrict__ pack,
        __half2* __restrict__ hsx, int N, int C) {
    __shared__ unsigned elist[CAPR];              // 16 KiB
    __shared__ int cnt[RNG];
    __shared__ int offs[RNG];
    __shared__ int cur[RNG];
    __shared__ float sdi[RNG];
    int t = threadIdx.x, r = blockIdx.x;
    if (t < RNG) cnt[t] = 0;
    __syncthreads();
    int m = min(gcur[r], CAPR);
    const unsigned* src = gbuf + ((size_t)r << CSH);
    for (int i = t; i < m; i += TPBS) {           // single global read of region
        unsigned p = src[i];
        elist[i] = p;
        atomicAdd(&cnt[p & (RNG - 1)], 1);
    }
    __syncthreads();
    if (t < RNG) offs[t] = cnt[t];
    __syncthreads();
    for (int off = 1; off < RNG; off <<= 1) {     // Hillis-Steele inclusive scan
        int v = 0;
        if (t < RNG && t >= off) v = offs[t - off];
        __syncthreads();
        if (t < RNG) offs[t] += v;
        __syncthreads();
    }
    if (t < RNG) {
        int ex = offs[t] - cnt[t];                // exclusive
        cur[t] = ex;
        sdi[t] = rsqrtf((float)cnt[t] + 1.0f);    // +1 self-loop
        int n = r * RNG + t;
        if (n < N) pack[n] = ((unsigned)ex << 16) | (unsigned)cnt[t];
    }
    __syncthreads();
    int rbase = r << CSH;
    for (int i = t; i < m; i += TPBS) {
        unsigned p = elist[i];
        int pos = rbase + atomicAdd(&cur[p & (RNG - 1)], 1);
        bucketS[pos] = (int)(p >> RSH);
    }
    // fused: hsx[n][:] = fp16(dinv[n] * x[n][:]) — 128 nodes x 8 half2
    for (int idx = t; idx < RNG * 8; idx += TPBS) {
        int ln = idx >> 3, f2 = idx & 7;
        int n = r * RNG + ln;
        if (n < N) {
            float2 xv = ((const float2*)x)[(size_t)n * 8 + f2];
            float dn = sdi[ln];
            hsx[(size_t)n * 8 + f2] = __floats2half2_rn(xv.x * dn, xv.y * dn);
        }
    }
}

// layer 1 + projection: nodes-in-lane gather (16 nodes/wave), register weights
__global__ void k_l1f(const int* __restrict__ bucketS, const unsigned* __restrict__ pack,
                      const uint2* __restrict__ hsx, const float* __restrict__ W1,
                      const float* __restrict__ b1, const float* __restrict__ Wf,
                      __half2* __restrict__ z, int N) {
    __shared__ __align__(16) float agg[4][16][16];   // [wave][node][feat]
    __shared__ __align__(16) float vrow[4][64];
    int t = threadIdx.x, wid = t >> 6, lane = t & 63;
    int part = lane >> 4, o = lane & 15;
    // register weights: lane j holds W1[:,j]; lane (part,o) holds Wf[part*16+j][o]
    float w1c[16], wfc[16];
#pragma unroll
    for (int k = 0; k < 16; k++) w1c[k] = W1[k * 64 + lane];
#pragma unroll
    for (int j = 0; j < 16; j++) wfc[j] = Wf[(part * 16 + j) * 16 + o];
    float b1v = b1[lane];
    int nodeG = (blockIdx.x * 4 + wid) * 16;      // 16 nodes per wave
    // gather: lane (n4,q) owns node nodeG+n4, slot q (8B of the 32B row)
    int n4 = lane >> 2, q = lane & 3;
    int n = nodeG + n4;
    bool valid = n < N;
    int base = 0, d = 0;
    if (valid) {
        unsigned p = pack[n];
        base = ((n >> RSH) << CSH) + (int)(p >> 16);
        d = (int)(p & 0xFFFF);
    }
    float a[4] = {0.f, 0.f, 0.f, 0.f};
    if (valid) acc4(a, hsx[(size_t)n * 4 + q]);   // self-loop
    int k = 0;
    for (; k + 1 < d; k += 2) {                   // 2 chains/lane, 128/wave
        int s0 = bucketS[base + k];
        int s1 = bucketS[base + k + 1];
        uint2 u0 = hsx[(size_t)s0 * 4 + q];
        uint2 u1 = hsx[(size_t)s1 * 4 + q];
        acc4(a, u0);
        acc4(a, u1);
    }
    if (k < d) acc4(a, hsx[(size_t)bucketS[base + k] * 4 + q]);
    *(float4*)&agg[wid][n4][q * 4] = make_float4(a[0], a[1], a[2], a[3]);
    // epilogue: 16 nodes batched; agg/vrow same-wave LDS roundtrips (b128)
    const float4* avp = (const float4*)agg[wid];
    const float4* vrp = (const float4*)vrow[wid];
#pragma unroll 4
    for (int nn = 0; nn < 16; nn++) {
        int node = nodeG + nn;
        if (node >= N) break;                     // wave-uniform
        float dn = rsqrtf((float)__shfl(d, nn * 4) + 1.0f);  // deg from owner lane
        float4 A0 = avp[nn * 4 + 0], A1 = avp[nn * 4 + 1];
        float4 A2 = avp[nn * 4 + 2], A3 = avp[nn * 4 + 3];
        float av[16] = {A0.x, A0.y, A0.z, A0.w, A1.x, A1.y, A1.z, A1.w,
                        A2.x, A2.y, A2.z, A2.w, A3.x, A3.y, A3.z, A3.w};
        float v = 0.f;
#pragma unroll
        for (int kk = 0; kk < 16; kk++) v += av[kk] * w1c[kk];
        v = fmaxf(dn * v + b1v, 0.f) * dn;        // lane j holds v_j
        vrow[wid][lane] = v;
        float4 V0 = vrp[part * 4 + 0], V1 = vrp[part * 4 + 1];
        float4 V2 = vrp[part * 4 + 2], V3 = vrp[part * 4 + 3];
        float vv[16] = {V0.x, V0.y, V0.z, V0.w, V1.x, V1.y, V1.z, V1.w,
                        V2.x, V2.y, V2.z, V2.w, V3.x, V3.y, V3.z, V3.w};
        float s = 0.f;
#pragma unroll
        for (int j = 0; j < 16; j++) s += vv[j] * wfc[j];
        s += __shfl_xor(s, 16);
        s += __shfl_xor(s, 32);                   // all lanes: z_o, o=lane&15
        float pv = __shfl(s, lane | 1);
        if (part == 0 && !(lane & 1))
            z[(size_t)node * 8 + (o >> 1)] = __floats2half2_rn(s, pv);
    }
}

// layer 2 aggregation of z + bias: pure nodes-in-lane gather, zero DS ops
__global__ void k_l3(const int* __restrict__ bucketS, const unsigned* __restrict__ pack,
                     const uint2* __restrict__ z, const float* __restrict__ bfv,
                     float* __restrict__ out, int N) {
    int t = threadIdx.x, wid = t >> 6, lane = t & 63;
    int n4 = lane >> 2, q = lane & 3;
    int n = (blockIdx.x * 4 + wid) * 16 + n4;
    if (n >= N) return;
    float4 bq = ((const float4*)bfv)[q];
    unsigned p = pack[n];
    int base = ((n >> RSH) << CSH) + (int)(p >> 16);
    int d = (int)(p & 0xFFFF);
    float a[4] = {0.f, 0.f, 0.f, 0.f};
    acc4(a, z[(size_t)n * 4 + q]);                // self-loop
    int k = 0;
    for (; k + 1 < d; k += 2) {
        int s0 = bucketS[base + k];
        int s1 = bucketS[base + k + 1];
        uint2 u0 = z[(size_t)s0 * 4 + q];
        uint2 u1 = z[(size_t)s1 * 4 + q];
        acc4(a, u0);
        acc4(a, u1);
    }
    if (k < d) acc4(a, z[(size_t)bucketS[base + k] * 4 + q]);
    float dn = rsqrtf((float)d + 1.0f);
    float4 r;
    r.x = dn * a[0] + bq.x;
    r.y = dn * a[1] + bq.y;
    r.z = dn * a[2] + bq.z;
    r.w = dn * a[3] + bq.w;
    ((float4*)out)[(size_t)n * 4 + q] = r;        // fully coalesced
}

extern "C" void kernel_launch(void* const* d_in, const int* in_sizes, int n_in,
                              void* d_out, int out_size, void* d_ws, size_t ws_size,
                              hipStream_t stream) {
    const float* x  = (const float*)d_in[0];
    const int*   ei = (const int*)d_in[1];
    const float* W1 = (const float*)d_in[2];
    const float* b1 = (const float*)d_in[3];
    const float* W2 = (const float*)d_in[4];
    const float* b2 = (const float*)d_in[5];
    const float* WL = (const float*)d_in[6];
    const float* bL = (const float*)d_in[7];
    float* out = (float*)d_out;

    const int N  = in_sizes[0] / 16;       // 100000
    const int E  = in_sizes[1] / 2;        // 1600000
    const int C  = (N + RNG - 1) >> RSH;   // 782 ranges
    const int NB = (E + EPB - 1) / EPB;    // 196 place blocks

    // ws ints: gbuf[C*CAPR] | bucketS[C*CAPR] | gcur[C] | pack[N] | pad
    //    then: Wf[1024] f32 | bf[16] | pad16B | hsx[8N] half2 | z[8N] half2
    int* wsi        = (int*)d_ws;
    unsigned* gbuf  = (unsigned*)wsi;
    int* bucketS    = wsi + ((size_t)C << CSH);
    int* gcur       = bucketS + ((size_t)C << CSH);
    unsigned* pack  = (unsigned*)(gcur + C);
    size_t off      = ((size_t)C << (CSH + 1)) + C + N;
    off = (off + 3) & ~(size_t)3;
    float* Wf    = (float*)(wsi + off);
    float* bf    = Wf + 1024;
    off = off + 1024 + 16;
    off = (off + 3) & ~(size_t)3;                 // 16B-align fp16 section
    __half2* hsx = (__half2*)(wsi + off);         // 8N half2
    __half2* z   = (__half2*)(wsi + off + (size_t)8 * N);

    // weight fusion + gcur zeroing (precedes k_place in stream order)
    k_wfuse<<<4, TPB, 0, stream>>>(W2, WL, b2, bL, Wf, bf, gcur, C);

    // ---- single-pass chunked placement into per-range regions ----
    k_place<<<NB, TPBP, 0, stream>>>(ei, gcur, gbuf, E, C);

    // ---- per-range node sort -> region CSR + pack + fp16 hsx ----
    k_sort2<<<C, TPBS, 0, stream>>>(gbuf, gcur, x, bucketS, pack, hsx, N, C);

    // ---- layer 1 + projection -> z fp16 [N,16] ----
    const int NBLK = (N + 63) / 64;               // 64 nodes per block (16/wave)
    k_l1f<<<NBLK, TPB, 0, stream>>>(bucketS, pack, (const uint2*)hsx, W1, b1, Wf, z, N);

    // ---- layer 2 aggregation + bias -> out ----
    k_l3<<<NBLK, TPB, 0, stream>>>(bucketS, pack, (const uint2*)z, bf, out, N);
}